// Round 1
// baseline (718.499 us; speedup 1.0000x reference)
//
#include <hip/hip_runtime.h>

#define NN 100000
#define EE 1600000
#define GG 64
#define HH 128
#define BN_EPS 1e-5f

// ---------------- graph prep ----------------

__global__ void k_count(const int* __restrict__ ei, int* __restrict__ cnt) {
    int e = blockIdx.x * blockDim.x + threadIdx.x;
    if (e < EE) atomicAdd(&cnt[ei[EE + e]], 1);
}

__global__ void k_dinv(const int* __restrict__ cnt, float* __restrict__ dinv) {
    int n = blockIdx.x * blockDim.x + threadIdx.x;
    if (n < NN) dinv[n] = rsqrtf((float)(cnt[n] + 1));   // +1 self loop; deg>=1 always
}

// exclusive scan of cnt -> offs, 1024 elems/block
__global__ void k_scan1(const int* __restrict__ cnt, int* __restrict__ offs,
                        int* __restrict__ bsum) {
    __shared__ int sh[256];
    int t = threadIdx.x;
    int base = blockIdx.x * 1024 + t * 4;
    int v0 = (base + 0 < NN) ? cnt[base + 0] : 0;
    int v1 = (base + 1 < NN) ? cnt[base + 1] : 0;
    int v2 = (base + 2 < NN) ? cnt[base + 2] : 0;
    int v3 = (base + 3 < NN) ? cnt[base + 3] : 0;
    int s0 = v0, s1 = s0 + v1, s2 = s1 + v2, s3 = s2 + v3;
    sh[t] = s3; __syncthreads();
    for (int d = 1; d < 256; d <<= 1) {
        int x = (t >= d) ? sh[t - d] : 0;
        __syncthreads();
        sh[t] += x;
        __syncthreads();
    }
    int excl = (t > 0) ? sh[t - 1] : 0;
    if (base + 0 < NN) offs[base + 0] = excl;
    if (base + 1 < NN) offs[base + 1] = excl + s0;
    if (base + 2 < NN) offs[base + 2] = excl + s1;
    if (base + 3 < NN) offs[base + 3] = excl + s2;
    if (t == 255) bsum[blockIdx.x] = sh[255];
}

__global__ void k_scan2(int* __restrict__ bsum, int nblk) {
    __shared__ int sh[128];
    int t = threadIdx.x;
    int v = (t < nblk) ? bsum[t] : 0;
    sh[t] = v; __syncthreads();
    for (int d = 1; d < 128; d <<= 1) {
        int x = (t >= d) ? sh[t - d] : 0;
        __syncthreads();
        sh[t] += x;
        __syncthreads();
    }
    int excl = (t > 0) ? sh[t - 1] : 0;
    if (t < nblk) bsum[t] = excl;
}

__global__ void k_scan3(int* __restrict__ offs, const int* __restrict__ bsum) {
    int i = blockIdx.x * blockDim.x + threadIdx.x;
    if (i < NN) offs[i] += bsum[i >> 10];
}

__global__ void k_bucket(const int* __restrict__ ei, const int* __restrict__ offs,
                         int* __restrict__ cursor, const float* __restrict__ dinv,
                         int* __restrict__ col, float* __restrict__ wgt) {
    int e = blockIdx.x * blockDim.x + threadIdx.x;
    if (e >= EE) return;
    int s = ei[e];
    int d = ei[EE + e];
    int p = offs[d] + atomicAdd(&cursor[d], 1);
    col[p] = s;
    wgt[p] = dinv[s] * dinv[d];
}

// ---------------- layer 1 (aggregate 3-dim input, then 4x128 matmul) ----------------

__global__ void k_aggx(const float* __restrict__ x, const int* __restrict__ offs,
                       const int* __restrict__ cnt, const int* __restrict__ col,
                       const float* __restrict__ wgt, const float* __restrict__ dinv,
                       float4* __restrict__ aggx) {
    int d = blockIdx.x * blockDim.x + threadIdx.x;
    if (d >= NN) return;
    float dv = dinv[d];
    float w0 = dv * dv;
    float a0 = x[d * 3 + 0] * w0;
    float a1 = x[d * 3 + 1] * w0;
    float a2 = x[d * 3 + 2] * w0;
    int base = offs[d], c = cnt[d];
    for (int i = 0; i < c; i++) {
        int s = col[base + i];
        float w = wgt[base + i];
        a0 += w * x[s * 3 + 0];
        a1 += w * x[s * 3 + 1];
        a2 += w * x[s * 3 + 2];
    }
    aggx[d] = make_float4(a0, a1, a2, 0.f);
}

#define L1R 16
__global__ void k_l1(const float4* __restrict__ aggx, const float* __restrict__ W1,
                     const float* __restrict__ b1, const float* __restrict__ g,
                     const float* __restrict__ bb, const float* __restrict__ m,
                     const float* __restrict__ v, float* __restrict__ out) {
    int c = threadIdx.x;                       // 0..127
    float w0 = W1[c], w1 = W1[128 + c], w2 = W1[256 + c];
    float sc = g[c] * rsqrtf(v[c] + BN_EPS);
    float sh = (b1[c] - m[c]) * sc + bb[c];
    int r0 = blockIdx.x * L1R;
    for (int i = 0; i < L1R; i++) {
        int n = r0 + i;
        if (n >= NN) break;
        float4 a = aggx[n];
        float t = a.x * w0 + a.y * w1 + a.z * w2;
        t = t * sc + sh;
        out[n * HH + c] = fmaxf(t, 0.f);
    }
}

// ---------------- dense 128x128 matmul (fp32 vector) ----------------
// 64 rows x 128 cols per block, 256 threads, thread = 8 rows x 4 cols

__global__ __launch_bounds__(256) void k_mm(const float* __restrict__ xin,
                                            const float* __restrict__ W,
                                            float* __restrict__ out) {
    __shared__ float xs[64][128];
    int tid = threadIdx.x;
    int tx = tid & 31;          // col group: cols 4*tx..4*tx+3
    int ty = tid >> 5;          // row group: rows ty*8..ty*8+7
    int row0 = blockIdx.x * 64;
#pragma unroll
    for (int i = 0; i < 8; i++) {
        int idx4 = i * 256 + tid;               // 0..2047 float4 slots
        int r = idx4 >> 5;
        int k4 = (idx4 & 31) * 4;
        int gr = row0 + r;
        float4 vv = (gr < NN) ? *(const float4*)&xin[gr * HH + k4]
                              : make_float4(0.f, 0.f, 0.f, 0.f);
        *(float4*)&xs[r][k4] = vv;
    }
    __syncthreads();
    float acc[8][4];
#pragma unroll
    for (int i = 0; i < 8; i++)
#pragma unroll
        for (int j = 0; j < 4; j++) acc[i][j] = 0.f;

    const float* Wp = W + tx * 4;
#pragma unroll 4
    for (int k = 0; k < 128; k++) {
        float4 w = *(const float4*)&Wp[k * HH];
#pragma unroll
        for (int i = 0; i < 8; i++) {
            float xv = xs[ty * 8 + i][k];
            acc[i][0] += xv * w.x;
            acc[i][1] += xv * w.y;
            acc[i][2] += xv * w.z;
            acc[i][3] += xv * w.w;
        }
    }
#pragma unroll
    for (int i = 0; i < 8; i++) {
        int gr = row0 + ty * 8 + i;
        if (gr < NN)
            *(float4*)&out[gr * HH + tx * 4] =
                make_float4(acc[i][0], acc[i][1], acc[i][2], acc[i][3]);
    }
}

// ---------------- gather-aggregate + bias + BN + ReLU ----------------
// one wave per node, lane holds 2 channels (float2), edge meta via shfl broadcast

__global__ __launch_bounds__(256) void k_agg(const float* __restrict__ t,
                                             const int* __restrict__ offs,
                                             const int* __restrict__ cnt,
                                             const int* __restrict__ col,
                                             const float* __restrict__ wgt,
                                             const float* __restrict__ dinv,
                                             const float* __restrict__ bias,
                                             const float* __restrict__ g,
                                             const float* __restrict__ bb,
                                             const float* __restrict__ m,
                                             const float* __restrict__ v,
                                             float* __restrict__ out) {
    int wave = threadIdx.x >> 6;
    int lane = threadIdx.x & 63;
    int d = blockIdx.x * 4 + wave;
    if (d >= NN) return;
    int c0 = lane * 2;
    float dv = dinv[d];
    float2 self = *(const float2*)&t[d * HH + c0];
    float a0 = self.x * dv * dv;
    float a1 = self.y * dv * dv;
    int base = offs[d], cn = cnt[d];
    for (int ib = 0; ib < cn; ib += 64) {
        int i = ib + lane;
        int s = 0;
        float w = 0.f;
        if (i < cn) { s = col[base + i]; w = wgt[base + i]; }
        int lim = min(64, cn - ib);
#pragma unroll 4
        for (int j = 0; j < lim; j++) {
            int ss = __shfl(s, j);
            float ww = __shfl(w, j);
            float2 tv = *(const float2*)&t[ss * HH + c0];
            a0 += ww * tv.x;
            a1 += ww * tv.y;
        }
    }
    float2 gg = *(const float2*)&g[c0];
    float2 vv = *(const float2*)&v[c0];
    float2 mm = *(const float2*)&m[c0];
    float2 bv = *(const float2*)&bb[c0];
    float2 bi = *(const float2*)&bias[c0];
    float sc0 = gg.x * rsqrtf(vv.x + BN_EPS);
    float sc1 = gg.y * rsqrtf(vv.y + BN_EPS);
    float o0 = a0 * sc0 + (bi.x - mm.x) * sc0 + bv.x;
    float o1 = a1 * sc1 + (bi.y - mm.y) * sc1 + bv.y;
    *(float2*)&out[d * HH + c0] = make_float2(fmaxf(o0, 0.f), fmaxf(o1, 0.f));
}

// ---------------- mean pool (batch sorted -> flush on graph change) ----------------

#define PBLK 512
__global__ void k_pool(const float* __restrict__ h, const int* __restrict__ batch,
                       float* __restrict__ gsum, int* __restrict__ gcnt) {
    int c = threadIdx.x;  // 128
    int per = (NN + PBLK - 1) / PBLK;
    int n0 = blockIdx.x * per;
    int n1 = min(NN, n0 + per);
    if (n0 >= NN) return;
    float acc = 0.f;
    int cur = batch[n0];
    int count = 0;
    for (int n = n0; n < n1; n++) {
        int gr = batch[n];
        if (gr != cur) {
            atomicAdd(&gsum[cur * HH + c], acc);
            if (c == 0) atomicAdd(&gcnt[cur], count);
            acc = 0.f; count = 0; cur = gr;
        }
        acc += h[n * HH + c];
        count++;
    }
    atomicAdd(&gsum[cur * HH + c], acc);
    if (c == 0) atomicAdd(&gcnt[cur], count);
}

__global__ void k_head(const float* __restrict__ gsum, const int* __restrict__ gcnt,
                       const float* __restrict__ linW, const float* __restrict__ linb,
                       float* __restrict__ out) {
    int t = threadIdx.x;        // 128 = 64 graphs x 2 outputs
    int gr = t >> 1, j = t & 1;
    float inv = 1.0f / fmaxf((float)gcnt[gr], 1.0f);
    float acc = 0.f;
    for (int c = 0; c < HH; c++) acc += gsum[gr * HH + c] * linW[c * 2 + j];
    out[t] = acc * inv + linb[j];
}

// ---------------- host launch ----------------

static inline size_t al256(size_t x) { return (x + 255) & ~(size_t)255; }

extern "C" void kernel_launch(void* const* d_in, const int* in_sizes, int n_in,
                              void* d_out, int out_size, void* d_ws, size_t ws_size,
                              hipStream_t stream) {
    const float* x    = (const float*)d_in[0];
    const int*   ei   = (const int*)d_in[1];
    const int*   batch= (const int*)d_in[2];
    const float* W1   = (const float*)d_in[3];
    const float* b1   = (const float*)d_in[4];
    const float* W2   = (const float*)d_in[5];
    const float* b2   = (const float*)d_in[6];
    const float* W3   = (const float*)d_in[7];
    const float* b3   = (const float*)d_in[8];
    const float* linW = (const float*)d_in[9];
    const float* linb = (const float*)d_in[10];
    const float* bn1g = (const float*)d_in[11];
    const float* bn1b = (const float*)d_in[12];
    const float* bn1m = (const float*)d_in[13];
    const float* bn1v = (const float*)d_in[14];
    const float* bn2g = (const float*)d_in[15];
    const float* bn2b = (const float*)d_in[16];
    const float* bn2m = (const float*)d_in[17];
    const float* bn2v = (const float*)d_in[18];
    const float* bn3g = (const float*)d_in[19];
    const float* bn3b = (const float*)d_in[20];
    const float* bn3m = (const float*)d_in[21];
    const float* bn3v = (const float*)d_in[22];
    float* out = (float*)d_out;

    char* ws = (char*)d_ws;
    size_t off = 0;
    int*    cnt    = (int*)(ws + off);    off += al256((size_t)NN * 4);
    int*    cursor = (int*)(ws + off);    off += al256((size_t)NN * 4);
    int*    offs   = (int*)(ws + off);    off += al256((size_t)NN * 4);
    int*    bsum   = (int*)(ws + off);    off += al256(128 * 4);
    float*  dinv   = (float*)(ws + off);  off += al256((size_t)NN * 4);
    int*    col    = (int*)(ws + off);    off += al256((size_t)EE * 4);
    float*  wgt    = (float*)(ws + off);  off += al256((size_t)EE * 4);
    float4* aggx   = (float4*)(ws + off); off += al256((size_t)NN * 16);
    float*  bufA   = (float*)(ws + off);  off += al256((size_t)NN * HH * 4);
    float*  bufB   = (float*)(ws + off);  off += al256((size_t)NN * HH * 4);
    float*  gsum   = (float*)(ws + off);  off += (size_t)GG * HH * 4;
    int*    gcnt   = (int*)(ws + off);    off += al256((size_t)GG * 4);

    hipMemsetAsync(cnt, 0, (size_t)NN * 4, stream);
    hipMemsetAsync(cursor, 0, (size_t)NN * 4, stream);
    hipMemsetAsync(gsum, 0, (size_t)GG * HH * 4 + (size_t)GG * 4, stream);

    int nblkE = (EE + 255) / 256;
    int nblkN = (NN + 255) / 256;
    int nblkScan = (NN + 1023) / 1024;   // 98

    k_count<<<nblkE, 256, 0, stream>>>(ei, cnt);
    k_dinv<<<nblkN, 256, 0, stream>>>(cnt, dinv);
    k_scan1<<<nblkScan, 256, 0, stream>>>(cnt, offs, bsum);
    k_scan2<<<1, 128, 0, stream>>>(bsum, nblkScan);
    k_scan3<<<nblkN, 256, 0, stream>>>(offs, bsum);
    k_bucket<<<nblkE, 256, 0, stream>>>(ei, offs, cursor, dinv, col, wgt);

    // layer 1: aggregate x (3-dim) then fused 4x128 matmul + BN + ReLU -> bufA
    k_aggx<<<nblkN, 256, 0, stream>>>(x, offs, cnt, col, wgt, dinv, aggx);
    k_l1<<<(NN + L1R - 1) / L1R, 128, 0, stream>>>(aggx, W1, b1, bn1g, bn1b, bn1m, bn1v, bufA);

    // layer 2: t = bufA @ W2 -> bufB ; aggregate + bias + BN + ReLU -> bufA
    k_mm<<<(NN + 63) / 64, 256, 0, stream>>>(bufA, W2, bufB);
    k_agg<<<NN / 4, 256, 0, stream>>>(bufB, offs, cnt, col, wgt, dinv,
                                      b2, bn2g, bn2b, bn2m, bn2v, bufA);

    // layer 3
    k_mm<<<(NN + 63) / 64, 256, 0, stream>>>(bufA, W3, bufB);
    k_agg<<<NN / 4, 256, 0, stream>>>(bufB, offs, cnt, col, wgt, dinv,
                                      b3, bn3g, bn3b, bn3m, bn3v, bufA);

    // pool + head
    k_pool<<<PBLK, 128, 0, stream>>>(bufA, batch, gsum, gcnt);
    k_head<<<1, 128, 0, stream>>>(gsum, gcnt, linW, linb, out);
}